// Round 15
// baseline (21.605 us; speedup 1.0000x reference)
//
#include <hip/hip_runtime.h>
#include <hip/hip_fp16.h>

// DeformConv2d: x[8,64,56,56], offset[8,18,56,56], weight[64,64,3,3] -> out[8,64,56,56]
// prep (NHWC fp16 x + swizzled fp16 w) -> fused gather+MFMA (asm-pinned depth-2, counted
// vmcnt, lgkm-only barriers, XCD batch-pinning). r15 change vs r14: TP 32->64 px/block
// (halves A-stream L2 traffic, amortizes metadata/barriers over 2x px). Wave = 1 og x
// 64 px (acc[4] column tiles); thread = 2 gather units/tap.

typedef _Float16 f16x8 __attribute__((ext_vector_type(8)));
typedef float    f32x4 __attribute__((ext_vector_type(4)));

namespace {
constexpr int Bn = 8, Cn = 64, Hn = 56, Wn = 56;
constexpr int Kk = 9, OCn = 64;
constexpr int NPIX = 56 * 56;      // 3136
constexpr int CK   = Cn * Kk;      // 576
constexpr int TP   = 64;           // px per block
constexpr int TILES = NPIX / TP;   // 49
constexpr int XTILES = NPIX / 64;  // 49 (prep transpose tiles)
constexpr int KSTEPS = CK / 32;    // 18
}

__device__ __forceinline__ __half2 u2h(unsigned u) {
    union { unsigned u; __half2 h; } x; x.u = u; return x.h;
}
__device__ __forceinline__ unsigned bcast_h(float f) {
    unsigned short hs = __half_as_ushort(__float2half(f));
    return (unsigned)hs * 0x10001u;
}
__device__ __forceinline__ void lds_barrier() {
    asm volatile("s_waitcnt lgkmcnt(0)" ::: "memory");
    __builtin_amdgcn_s_barrier();
}
// Position-pinned 16B global load (async; pair with explicit vmcnt waits).
__device__ __forceinline__ void gld16(uint4& d, const unsigned short* p) {
    asm volatile("global_load_dwordx4 %0, %1, off" : "=&v"(d) : "v"(p) : "memory");
}

// prep: blocks [0,392): x NCHW fp32 -> NHWC fp16, batch = blk&7 (XCD-pinned).
//       blocks [392,536): w -> wh2 A-frag layout.
// wh2 uint4 index ((og*18+kk)*64+lane) = w[oc=og*16+(lane&15)][kglob=kk*32+(lane>>4)*8+j],
// kglob = tap*64 + c.
__global__ __launch_bounds__(256) void prep_kernel(
    const float* __restrict__ x, const float* __restrict__ w,
    unsigned short* __restrict__ xh, unsigned short* __restrict__ wh2)
{
    const int tid = threadIdx.x;
    if (blockIdx.x >= 392) {
        const int i = (blockIdx.x - 392) * 256 + tid;
        if (i < OCn * CK) {
            const int j    = i & 7;
            const int lane = (i >> 3) & 63;
            const int rest = i >> 9;           // og*18 + kk
            const int og   = rest / KSTEPS;
            const int oc   = og * 16 + (lane & 15);
            const int kglob = (rest % KSTEPS) * 32 + (lane >> 4) * 8 + j;
            const int tap = kglob >> 6;
            const int c   = kglob & 63;
            wh2[i] = __half_as_ushort(__float2half(w[oc * CK + c * Kk + tap]));
        }
        return;
    }
    __shared__ unsigned short lds[64][66];
    const int b  = blockIdx.x & 7;             // XCD-pinned batch
    const int t0 = (blockIdx.x >> 3) * 64;     // transpose tile within batch
    const float* xb = x + (size_t)b * Cn * NPIX;
    {
        const int hw0 = (tid & 15) * 4;
        #pragma unroll
        for (int i = 0; i < 4; ++i) {
            const int c = (tid >> 4) + i * 16;
            const float4 v = *(const float4*)(xb + (size_t)c * NPIX + t0 + hw0);
            lds[hw0 + 0][c] = __half_as_ushort(__float2half(v.x));
            lds[hw0 + 1][c] = __half_as_ushort(__float2half(v.y));
            lds[hw0 + 2][c] = __half_as_ushort(__float2half(v.z));
            lds[hw0 + 3][c] = __half_as_ushort(__float2half(v.w));
        }
    }
    __syncthreads();
    {
        const int co = (tid & 7) * 8;
        #pragma unroll
        for (int i = 0; i < 2; ++i) {
            const int hw = (tid >> 3) + i * 32;
            unsigned short tmp[8] __attribute__((aligned(16)));
            #pragma unroll
            for (int j = 0; j < 8; ++j) tmp[j] = lds[hw][co + j];
            *(uint4*)(xh + ((size_t)b * NPIX + t0 + hw) * Cn + co) = *(const uint4*)tmp;
        }
    }
}

// Fused: block = 64 px x 64 oc, 256 threads (4 waves). batch = blk&7, tile = blk>>3.
// Wave = og (16 oc) x 64 px; thread = 2 gather units per tap.
__global__ __launch_bounds__(256, 3) void deform_fused(
    const unsigned short* __restrict__ xh, const float* __restrict__ off,
    const unsigned short* __restrict__ wh2, float* __restrict__ out)
{
    __shared__ uint4 smpw[Kk * TP];            // 9216 B
    __shared__ int4  smpa[Kk * TP];            // 9216 B
    __shared__ __align__(16) uint4 vbuf[3][8 * TP];   // 24576 B

    const int tid = threadIdx.x;
    const int b  = blockIdx.x & 7;             // XCD-pinned batch
    const int p0 = (blockIdx.x >> 3) * TP;     // px tile within batch
    const unsigned short* xb = xh + (size_t)b * NPIX * Cn;
    const float* offb = off + (size_t)b * 18 * NPIX;

    // ---- metadata: entry per (tap, px), 576 entries ----
    for (int e = tid; e < Kk * TP; e += 256) {
        const int k  = e >> 6;
        const int px = e & 63;
        const int p  = p0 + px;
        const int oy = p / Wn, ox = p % Wn;
        const int ki = k / 3, kj = k % 3;
        const float offy = offb[(size_t)(2 * k)     * NPIX + p];
        const float offx = offb[(size_t)(2 * k + 1) * NPIX + p];
        const float py  = offy + (float)(oy - 1 + ki);
        const float pxv = offx + (float)(ox - 1 + kj);
        const float y0f = floorf(py), x0f = floorf(pxv);
        const float ty = py - y0f, tx = pxv - x0f;
        const int y0 = (int)y0f, x0 = (int)x0f;
        const int y1 = y0 + 1, x1 = x0 + 1;
        const bool vy0 = (y0 >= 0) & (y0 < Hn);
        const bool vy1 = (y1 >= 0) & (y1 < Hn);
        const bool vx0 = (x0 >= 0) & (x0 < Wn);
        const bool vx1 = (x1 >= 0) & (x1 < Wn);
        const int cy0 = min(max(y0, 0), Hn - 1);
        const int cy1 = min(max(y1, 0), Hn - 1);
        const int cx0 = min(max(x0, 0), Wn - 1);
        const int cx1 = min(max(x1, 0), Wn - 1);
        uint4 wq;
        wq.x = bcast_h((vy0 && vx0) ? (1.f - ty) * (1.f - tx) : 0.f);
        wq.y = bcast_h((vy0 && vx1) ? (1.f - ty) * tx         : 0.f);
        wq.z = bcast_h((vy1 && vx0) ? ty * (1.f - tx)         : 0.f);
        wq.w = bcast_h((vy1 && vx1) ? ty * tx                 : 0.f);
        int4 av;
        av.x = (cy0 * Wn + cx0) * Cn;
        av.y = (cy0 * Wn + cx1) * Cn;
        av.z = (cy1 * Wn + cx0) * Cn;
        av.w = (cy1 * Wn + cx1) * Cn;
        smpw[e] = wq;
        smpa[e] = av;
    }
    lds_barrier();
    asm volatile("s_waitcnt vmcnt(0)" ::: "memory");   // zero the counter

    // thread -> 2 gather units: oct = tid&7, px = gpx0 and gpx0+32
    const int oct  = tid & 7;
    const int gpx0 = (tid >> 3) & 31;
    const int co   = oct * 8;

    // GEMM ids: wave = og (16 oc) x 64 px (4 column tiles)
    const int lane = tid & 63;
    const int og   = tid >> 6;
    const int hi   = lane >> 4;
    const int lr   = lane & 15;
    const uint4* ab = (const uint4*)wh2 + (size_t)og * KSTEPS * 64 + lane;

    uint4 s0[2][2], s1[2][2], s2[2][2], s3[2][2], wqr[2][2];  // [slot][unit]
    uint4 aF[2][2];                                            // [slot][kl]
    f32x4 acc[4] = {{0.f,0.f,0.f,0.f},{0.f,0.f,0.f,0.f},
                    {0.f,0.f,0.f,0.f},{0.f,0.f,0.f,0.f}};

    auto stageC = [&](int k) {                  // 8 pinned corner loads (2 units)
        const int sl = k & 1;
        #pragma unroll
        for (int u = 0; u < 2; ++u) {
            const int m  = k * TP + gpx0 + u * 32;
            const int4 av = smpa[m];
            wqr[sl][u] = smpw[m];
            gld16(s0[sl][u], xb + av.x + co);
            gld16(s1[sl][u], xb + av.y + co);
            gld16(s2[sl][u], xb + av.z + co);
            gld16(s3[sl][u], xb + av.w + co);
        }
    };
    auto loadA = [&](int k) {                   // 2 pinned A loads for tap k
        const int sl = k & 1;
        gld16(aF[sl][0], (const unsigned short*)(ab + (k * 2 + 0) * 64));
        gld16(aF[sl][1], (const unsigned short*)(ab + (k * 2 + 1) * 64));
    };
    auto blend = [&](int k) {
        const int sl = k & 1;
        #pragma unroll
        for (int u = 0; u < 2; ++u) {
            const __half2 w00 = u2h(wqr[sl][u].x), w01 = u2h(wqr[sl][u].y);
            const __half2 w10 = u2h(wqr[sl][u].z), w11 = u2h(wqr[sl][u].w);
            uint4 res;
            unsigned* rp = (unsigned*)&res;
            #pragma unroll
            for (int q = 0; q < 4; ++q) {
                __half2 a = __hmul2(w00, u2h(((const unsigned*)&s0[sl][u])[q]));
                a = __hfma2(w01, u2h(((const unsigned*)&s1[sl][u])[q]), a);
                a = __hfma2(w10, u2h(((const unsigned*)&s2[sl][u])[q]), a);
                a = __hfma2(w11, u2h(((const unsigned*)&s3[sl][u])[q]), a);
                rp[q] = *(const unsigned*)&a;
            }
            vbuf[k % 3][oct * TP + gpx0 + u * 32] = res;
        }
    };
    auto mfma = [&](int k) {
        const int sl = k % 3;
        #pragma unroll
        for (int kl = 0; kl < 2; ++kl) {
            const int octr = kl * 4 + hi;
            union { uint4 u; f16x8 h; } a;
            a.u = aF[k & 1][kl];
            #pragma unroll
            for (int ct = 0; ct < 4; ++ct) {
                union { uint4 u; f16x8 h; } bb;
                bb.u = vbuf[sl][octr * TP + ct * 16 + lr];
                acc[ct] = __builtin_amdgcn_mfma_f32_16x16x32_f16(a.h, bb.h, acc[ct], 0, 0, 0);
            }
        }
    };

    // prologue: corners(0,1) + A(0) in flight (18 outstanding)
    stageC(0); stageC(1);
    loadA(0);
    asm volatile("s_waitcnt vmcnt(10)" ::: "memory");   // corner(0) landed
    __builtin_amdgcn_sched_barrier(0);
    blend(0);
    lds_barrier();

    #pragma unroll
    for (int k = 0; k < Kk; ++k) {
        if (k < Kk - 2) stageC(k + 2);       // +8
        if (k < Kk - 1) loadA(k + 1);        // +2
        if (k < Kk - 2)       asm volatile("s_waitcnt vmcnt(10)" ::: "memory");
        else if (k == Kk - 2) asm volatile("s_waitcnt vmcnt(2)"  ::: "memory");
        else                  asm volatile("s_waitcnt vmcnt(0)"  ::: "memory");
        __builtin_amdgcn_sched_barrier(0);
        if (k < Kk - 1) blend(k + 1);        // corner(k+1) guaranteed landed
        mfma(k);                             // aF[k] guaranteed landed
        lds_barrier();
    }

    // D: col(px)=ct*16+lr, row(oc within 16)=hi*4+r
    #pragma unroll
    for (int ct = 0; ct < 4; ++ct) {
        float* ob = out + ((size_t)b * OCn + og * 16 + hi * 4) * NPIX + p0 + ct * 16 + lr;
        #pragma unroll
        for (int r = 0; r < 4; ++r) ob[(size_t)r * NPIX] = acc[ct][r];
    }
}

extern "C" void kernel_launch(void* const* d_in, const int* in_sizes, int n_in,
                              void* d_out, int out_size, void* d_ws, size_t ws_size,
                              hipStream_t stream) {
    const float* x   = (const float*)d_in[0];
    const float* off = (const float*)d_in[1];
    const float* w   = (const float*)d_in[2];
    float* out = (float*)d_out;
    unsigned short* wh2 = (unsigned short*)d_ws;                    // 73728 B
    unsigned short* xh  = (unsigned short*)((char*)d_ws + 131072);  // 3.21 MB

    hipLaunchKernelGGL(prep_kernel, dim3(392 + 144), dim3(256), 0, stream, x, w, xh, wh2);
    hipLaunchKernelGGL(deform_fused, dim3(Bn * TILES), dim3(256), 0, stream,
                       xh, off, wh2, out);
}

// Round 16
// 20.457 us; speedup vs baseline: 1.0561x; 1.0561x over previous
//
#include <hip/hip_runtime.h>
#include <hip/hip_fp16.h>

// DeformConv2d: x[8,64,56,56], offset[8,18,56,56], weight[64,64,3,3] -> out[8,64,56,56]
// prep (NHWC fp16 x + swizzled fp16 w) -> fused gather+MFMA (asm-pinned depth-2, counted
// vmcnt, lgkm-only barriers, XCD batch-pinning). r16 change vs r14: 2-D 8x4 px tiles
// (sample window ~18 KB fits L1; 1-D 32-px strips had ~34 KB windows that thrashed L1).

typedef _Float16 f16x8 __attribute__((ext_vector_type(8)));
typedef float    f32x4 __attribute__((ext_vector_type(4)));

namespace {
constexpr int Bn = 8, Cn = 64, Hn = 56, Wn = 56;
constexpr int Kk = 9, OCn = 64;
constexpr int NPIX = 56 * 56;      // 3136
constexpr int CK   = Cn * Kk;      // 576
constexpr int TP   = 32;           // px per block (8 wide x 4 tall)
constexpr int TXW  = 7;            // tiles across (56/8)
constexpr int TILES = 98;          // 7 x 14
constexpr int XTILES = NPIX / 64;  // 49 (prep transpose tiles)
constexpr int KSTEPS = CK / 32;    // 18
}

__device__ __forceinline__ __half2 u2h(unsigned u) {
    union { unsigned u; __half2 h; } x; x.u = u; return x.h;
}
__device__ __forceinline__ unsigned bcast_h(float f) {
    unsigned short hs = __half_as_ushort(__float2half(f));
    return (unsigned)hs * 0x10001u;
}
__device__ __forceinline__ void lds_barrier() {
    asm volatile("s_waitcnt lgkmcnt(0)" ::: "memory");
    __builtin_amdgcn_s_barrier();
}
// Position-pinned 16B global load (async; pair with explicit vmcnt waits).
__device__ __forceinline__ void gld16(uint4& d, const unsigned short* p) {
    asm volatile("global_load_dwordx4 %0, %1, off" : "=&v"(d) : "v"(p) : "memory");
}

// prep: blocks [0,392): x NCHW fp32 -> NHWC fp16, batch = blk&7 (XCD-pinned).
//       blocks [392,536): w -> wh2 A-frag layout.
// wh2 uint4 index ((og*18+kk)*64+lane) = w[oc=og*16+(lane&15)][kglob=kk*32+(lane>>4)*8+j],
// kglob = tap*64 + c.
__global__ __launch_bounds__(256) void prep_kernel(
    const float* __restrict__ x, const float* __restrict__ w,
    unsigned short* __restrict__ xh, unsigned short* __restrict__ wh2)
{
    const int tid = threadIdx.x;
    if (blockIdx.x >= 392) {
        const int i = (blockIdx.x - 392) * 256 + tid;
        if (i < OCn * CK) {
            const int j    = i & 7;
            const int lane = (i >> 3) & 63;
            const int rest = i >> 9;           // og*18 + kk
            const int og   = rest / KSTEPS;
            const int oc   = og * 16 + (lane & 15);
            const int kglob = (rest % KSTEPS) * 32 + (lane >> 4) * 8 + j;
            const int tap = kglob >> 6;
            const int c   = kglob & 63;
            wh2[i] = __half_as_ushort(__float2half(w[oc * CK + c * Kk + tap]));
        }
        return;
    }
    __shared__ unsigned short lds[64][66];
    const int b  = blockIdx.x & 7;             // XCD-pinned batch
    const int t0 = (blockIdx.x >> 3) * 64;     // transpose tile within batch
    const float* xb = x + (size_t)b * Cn * NPIX;
    {
        const int hw0 = (tid & 15) * 4;
        #pragma unroll
        for (int i = 0; i < 4; ++i) {
            const int c = (tid >> 4) + i * 16;
            const float4 v = *(const float4*)(xb + (size_t)c * NPIX + t0 + hw0);
            lds[hw0 + 0][c] = __half_as_ushort(__float2half(v.x));
            lds[hw0 + 1][c] = __half_as_ushort(__float2half(v.y));
            lds[hw0 + 2][c] = __half_as_ushort(__float2half(v.z));
            lds[hw0 + 3][c] = __half_as_ushort(__float2half(v.w));
        }
    }
    __syncthreads();
    {
        const int co = (tid & 7) * 8;
        #pragma unroll
        for (int i = 0; i < 2; ++i) {
            const int hw = (tid >> 3) + i * 32;
            unsigned short tmp[8] __attribute__((aligned(16)));
            #pragma unroll
            for (int j = 0; j < 8; ++j) tmp[j] = lds[hw][co + j];
            *(uint4*)(xh + ((size_t)b * NPIX + t0 + hw) * Cn + co) = *(const uint4*)tmp;
        }
    }
}

// Fused: block = 8x4 px tile x 64 oc, 256 threads. batch = blk&7, tile = blk>>3.
__global__ __launch_bounds__(256, 3) void deform_fused(
    const unsigned short* __restrict__ xh, const float* __restrict__ off,
    const unsigned short* __restrict__ wh2, float* __restrict__ out)
{
    __shared__ uint4 smpw[Kk * TP];            // 4608 B
    __shared__ int4  smpa[Kk * TP];            // 4608 B
    __shared__ __align__(16) uint4 vbuf[3][8 * TP];   // 12288 B

    const int tid = threadIdx.x;
    const int b   = blockIdx.x & 7;            // XCD-pinned batch
    const int t   = blockIdx.x >> 3;           // 0..97
    const int ox0 = (t % TXW) * 8;             // tile origin x
    const int oy0 = (t / TXW) * 4;             // tile origin y
    const unsigned short* xb = xh + (size_t)b * NPIX * Cn;
    const float* offb = off + (size_t)b * 18 * NPIX;

    // ---- metadata: entry per (tap, px), 288 entries; px -> (oy0+px>>3, ox0+px&7) ----
    for (int e = tid; e < Kk * TP; e += 256) {
        const int k  = e >> 5;
        const int px = e & 31;
        const int oy = oy0 + (px >> 3);
        const int ox = ox0 + (px & 7);
        const int p  = oy * Wn + ox;
        const int ki = k / 3, kj = k % 3;
        const float offy = offb[(size_t)(2 * k)     * NPIX + p];
        const float offx = offb[(size_t)(2 * k + 1) * NPIX + p];
        const float py  = offy + (float)(oy - 1 + ki);
        const float pxv = offx + (float)(ox - 1 + kj);
        const float y0f = floorf(py), x0f = floorf(pxv);
        const float ty = py - y0f, tx = pxv - x0f;
        const int y0 = (int)y0f, x0 = (int)x0f;
        const int y1 = y0 + 1, x1 = x0 + 1;
        const bool vy0 = (y0 >= 0) & (y0 < Hn);
        const bool vy1 = (y1 >= 0) & (y1 < Hn);
        const bool vx0 = (x0 >= 0) & (x0 < Wn);
        const bool vx1 = (x1 >= 0) & (x1 < Wn);
        const int cy0 = min(max(y0, 0), Hn - 1);
        const int cy1 = min(max(y1, 0), Hn - 1);
        const int cx0 = min(max(x0, 0), Wn - 1);
        const int cx1 = min(max(x1, 0), Wn - 1);
        uint4 wq;
        wq.x = bcast_h((vy0 && vx0) ? (1.f - ty) * (1.f - tx) : 0.f);
        wq.y = bcast_h((vy0 && vx1) ? (1.f - ty) * tx         : 0.f);
        wq.z = bcast_h((vy1 && vx0) ? ty * (1.f - tx)         : 0.f);
        wq.w = bcast_h((vy1 && vx1) ? ty * tx                 : 0.f);
        int4 av;
        av.x = (cy0 * Wn + cx0) * Cn;
        av.y = (cy0 * Wn + cx1) * Cn;
        av.z = (cy1 * Wn + cx0) * Cn;
        av.w = (cy1 * Wn + cx1) * Cn;
        smpw[e] = wq;
        smpa[e] = av;
    }
    lds_barrier();
    asm volatile("s_waitcnt vmcnt(0)" ::: "memory");   // zero the counter

    // thread -> gather unit: oct = tid&7, px = (tid>>3)&31
    const int oct = tid & 7;
    const int gpx = (tid >> 3) & 31;
    const int co  = oct * 8;

    // GEMM ids: wave = og (16 oc) x 32 px
    const int lane = tid & 63;
    const int og   = tid >> 6;
    const int hi   = lane >> 4;
    const int lr   = lane & 15;
    const uint4* ab = (const uint4*)wh2 + (size_t)og * KSTEPS * 64 + lane;

    uint4 s0[2], s1[2], s2[2], s3[2], wqr[2];   // corner staging, slot = k&1
    uint4 aF[2][2];                              // A prefetch, slot = k&1
    f32x4 acc0 = {0.f, 0.f, 0.f, 0.f};
    f32x4 acc1 = {0.f, 0.f, 0.f, 0.f};

    auto stageC = [&](int k) {                  // 4 pinned corner loads for tap k
        const int sl = k & 1;
        const int m  = k * TP + gpx;
        const int4 av = smpa[m];
        wqr[sl] = smpw[m];
        gld16(s0[sl], xb + av.x + co);
        gld16(s1[sl], xb + av.y + co);
        gld16(s2[sl], xb + av.z + co);
        gld16(s3[sl], xb + av.w + co);
    };
    auto loadA = [&](int k) {                   // 2 pinned A loads for tap k
        const int sl = k & 1;
        gld16(aF[sl][0], (const unsigned short*)(ab + (k * 2 + 0) * 64));
        gld16(aF[sl][1], (const unsigned short*)(ab + (k * 2 + 1) * 64));
    };
    auto blend = [&](int k) {
        const int sl = k & 1;
        const __half2 w00 = u2h(wqr[sl].x), w01 = u2h(wqr[sl].y);
        const __half2 w10 = u2h(wqr[sl].z), w11 = u2h(wqr[sl].w);
        uint4 res;
        unsigned* rp = (unsigned*)&res;
        #pragma unroll
        for (int q = 0; q < 4; ++q) {
            __half2 a = __hmul2(w00, u2h(((const unsigned*)&s0[sl])[q]));
            a = __hfma2(w01, u2h(((const unsigned*)&s1[sl])[q]), a);
            a = __hfma2(w10, u2h(((const unsigned*)&s2[sl])[q]), a);
            a = __hfma2(w11, u2h(((const unsigned*)&s3[sl])[q]), a);
            rp[q] = *(const unsigned*)&a;
        }
        vbuf[k % 3][oct * TP + gpx] = res;
    };
    auto mfma = [&](int k) {
        const int sl = k % 3;
        #pragma unroll
        for (int kl = 0; kl < 2; ++kl) {
            const int octr = kl * 4 + hi;
            union { uint4 u; f16x8 h; } a, b0, b1;
            a.u  = aF[k & 1][kl];
            b0.u = vbuf[sl][octr * TP + lr];
            b1.u = vbuf[sl][octr * TP + 16 + lr];
            acc0 = __builtin_amdgcn_mfma_f32_16x16x32_f16(a.h, b0.h, acc0, 0, 0, 0);
            acc1 = __builtin_amdgcn_mfma_f32_16x16x32_f16(a.h, b1.h, acc1, 0, 0, 0);
        }
    };

    // prologue: corners(0,1) + A(0) in flight (10 outstanding)
    stageC(0); stageC(1);
    loadA(0);
    asm volatile("s_waitcnt vmcnt(6)" ::: "memory");   // corner(0) landed
    __builtin_amdgcn_sched_barrier(0);
    blend(0);
    lds_barrier();

    #pragma unroll
    for (int k = 0; k < Kk; ++k) {
        if (k < Kk - 2) stageC(k + 2);       // +4
        if (k < Kk - 1) loadA(k + 1);        // +2
        if (k < Kk - 2)      asm volatile("s_waitcnt vmcnt(6)" ::: "memory");
        else if (k == Kk - 2) asm volatile("s_waitcnt vmcnt(2)" ::: "memory");
        else                  asm volatile("s_waitcnt vmcnt(0)" ::: "memory");
        __builtin_amdgcn_sched_barrier(0);
        if (k < Kk - 1) blend(k + 1);        // corner(k+1) guaranteed landed
        mfma(k);                             // aF[k] guaranteed landed
        lds_barrier();
    }

    // D: px' = lr (and 16+lr) -> (oy0 + px'>>3, ox0 + px'&7); row(oc) = og*16+hi*4+r
    const int p_lo = (oy0 + (lr >> 3)) * Wn + ox0 + (lr & 7);
    const int p_hi = (oy0 + 2 + (lr >> 3)) * Wn + ox0 + (lr & 7);   // px 16..31
    float* ob = out + ((size_t)b * OCn + og * 16 + hi * 4) * NPIX;
    #pragma unroll
    for (int r = 0; r < 4; ++r) {
        ob[(size_t)r * NPIX + p_lo] = acc0[r];
        ob[(size_t)r * NPIX + p_hi] = acc1[r];
    }
}

extern "C" void kernel_launch(void* const* d_in, const int* in_sizes, int n_in,
                              void* d_out, int out_size, void* d_ws, size_t ws_size,
                              hipStream_t stream) {
    const float* x   = (const float*)d_in[0];
    const float* off = (const float*)d_in[1];
    const float* w   = (const float*)d_in[2];
    float* out = (float*)d_out;
    unsigned short* wh2 = (unsigned short*)d_ws;                    // 73728 B
    unsigned short* xh  = (unsigned short*)((char*)d_ws + 131072);  // 3.21 MB

    hipLaunchKernelGGL(prep_kernel, dim3(392 + 144), dim3(256), 0, stream, x, w, xh, wh2);
    hipLaunchKernelGGL(deform_fused, dim3(Bn * TILES), dim3(256), 0, stream,
                       xh, off, wh2, out);
}